// Round 6
// baseline (157.034 us; speedup 1.0000x reference)
//
#include <hip/hip_runtime.h>
#include <hip/hip_bf16.h>

// loss = mean_n( logsumexp([pos_n, (online@queue)_n]/t) - pos_n/t )   (fwd: alpha mix = identity)
// v14 = v11 shape (512 thr, wave=32rowsx128cols, 4 waves/SIMD, single staging barrier)
//   with 32x32x16 MFMA instead of 16x16x32: half the K-loop instructions, -17% MFMA
//   pipe time (2382 vs 2075 TF ceiling), same LDS bytes/width/bank profile, acc still
//   64 AGPR. Epilogue redone for the 32x32 C layout (col=lane&31,
//   row=(reg&3)+8*(reg>>2)+4*(lane>>5)); (M,S) parked in 8KB smP, coalesced store pass.
//   v13 post-mortem: A-ping-pong null -> attack issue count, not load latency.

#define NROWS 1024
#define DDIM  256
#define KQ    65536
#define BN    128
#define NPART 512
#define LN2_F 0.69314718055994531f

typedef short  short8   __attribute__((ext_vector_type(8)));
typedef float  floatx4  __attribute__((ext_vector_type(4)));
typedef float  floatx2  __attribute__((ext_vector_type(2)));
typedef float  floatx16 __attribute__((ext_vector_type(16)));

__device__ __forceinline__ unsigned short f2bf(float f) {
    unsigned int u = __float_as_uint(f);
    u += 0x7FFFu + ((u >> 16) & 1u);   // RNE
    return (unsigned short)(u >> 16);
}

// DPP lane-permute (row-of-16 scope). quad_perm xor1=0xB1, xor2=0x4E,
// row_half_mirror=0x141 (pairs quads), row_mirror=0x140 (pairs octets).
#define DPPMOV(x, ctrl) \
    __uint_as_float(__builtin_amdgcn_mov_dpp(__float_as_uint(x), (ctrl), 0xF, 0xF, true))

__device__ __forceinline__ float dpp16_max(float x) {
    x = fmaxf(x, DPPMOV(x, 0xB1));
    x = fmaxf(x, DPPMOV(x, 0x4E));
    x = fmaxf(x, DPPMOV(x, 0x141));
    x = fmaxf(x, DPPMOV(x, 0x140));
    return x;   // all 16 lanes of the row-of-16 hold the max
}
__device__ __forceinline__ float dpp16_sum(float x) {
    x += DPPMOV(x, 0xB1);
    x += DPPMOV(x, 0x4E);
    x += DPPMOV(x, 0x141);
    x += DPPMOV(x, 0x140);
    return x;
}

// ---- A conversion: bf16(A/(t*ln2)); also zeroes the output accumulator ----
__global__ __launch_bounds__(256)
void conv_a(const float* __restrict__ A, const float* __restrict__ temp,
            unsigned short* __restrict__ Ab, float* __restrict__ out)
{
    if (blockIdx.x == 0 && threadIdx.x == 0) out[0] = 0.0f;
    const float s = 1.0f / (temp[0] * LN2_F);
    const int i = blockIdx.x * 256 + threadIdx.x;       // 65536 threads, one float4 each
    const floatx4 v = ((const floatx4*)A)[i];
    ushort4 w;
    w.x = f2bf(v.x * s); w.y = f2bf(v.y * s);
    w.z = f2bf(v.z * s); w.w = f2bf(v.w * s);
    ((ushort4*)Ab)[i] = w;
}

// ---- fused GEMM + online-softmax partials. 512 blocks x 512 thr; block = one 128-col stripe ----
__global__ __launch_bounds__(512, 4)
void gemm_softmax(const unsigned short* __restrict__ Ab,   // [1024][256] bf16, pre-scaled
                  const float* __restrict__ Q,             // [256][65536] fp32
                  float2* __restrict__ partials)           // [NPART][1024]  (part-major)
{
    __shared__ __align__(16) unsigned short Bl[BN * DDIM];   // [n][k] bf16, 64 KB, swizzled
    __shared__ __align__(16) float2 smP[NROWS];              // 8 KB per-row (M,S)

    const int tid  = threadIdx.x;
    const int lane = tid & 63;
    const int wave = tid >> 6;          // 0..7 (32-row bands within a group-pass)
    const int l15  = lane & 15;
    const int l31  = lane & 31;
    const int hw   = lane >> 5;         // half-wave 0/1
    const int nb   = blockIdx.x;        // 0..511
    const int nbase = nb * BN;

    // ---- stage B once: Q[k][nbase..+127] fp32 -> Bl[n][k] bf16 (register transpose) ----
    // 1024 tasks (ko-octet x ny-quad), 2 per thread, one at a time (32 VGPR peak).
    #pragma unroll 1
    for (int iter = 0; iter < 2; ++iter) {
        const int t2 = iter * 512 + tid;
        const int ny = t2 & 31;             // n-quad (4 cols)
        const int ko = t2 >> 5;             // k-octet (8 rows), 0..31
        floatx4 v[8];
        #pragma unroll
        for (int j = 0; j < 8; ++j)
            v[j] = __builtin_nontemporal_load(
                       (const floatx4*)(Q + (size_t)(ko * 8 + j) * KQ + nbase + ny * 4));
        #pragma unroll
        for (int i2 = 0; i2 < 4; ++i2) {
            const int n = ny * 4 + i2;
            const int phys = ko ^ (n & 15);      // 16B-chunk XOR swizzle
            short8 w;
            #pragma unroll
            for (int j = 0; j < 8; ++j)
                w[j] = (short)f2bf(v[j][i2]);
            *(short8*)&Bl[n * DDIM + phys * 8] = w;
        }
    }
    __syncthreads();

    #pragma unroll 1
    for (int g = 0; g < 4; ++g) {
        const int rowbase = g * 256 + wave * 32;
        // A frag (32x32x16): lane row = l31, k = hw*8 + e, step adds s*16
        const unsigned short* apb = Ab + (size_t)(rowbase + l31) * DDIM + hw * 8;

        floatx16 acc[4] = {};
        short8 af, bf[4];

        #pragma unroll 1
        for (int s = 0; s < 16; ++s) {
            af = *(const short8*)(apb + s * 16);
            // B frag: n = j*32 + l31, k-chunk = 2s + hw, phys = chunk ^ (n&15), n&15 == l15
            const int vb = l31 * 512 + (((2 * s + hw) ^ l15) * 16);
            #pragma unroll
            for (int j = 0; j < 4; ++j)
                bf[j] = *(const short8*)((const char*)Bl + vb + j * 16384);
            #pragma unroll
            for (int j = 0; j < 4; ++j)
                acc[j] = __builtin_amdgcn_mfma_f32_32x32x16_bf16(af, bf[j], acc[j], 0, 0, 0);
        }

        // epilogue: base-2 logits. C layout (32x32): col=lane&31,
        // row = (reg&3) + 8*(reg>>2) + 4*hw  (rows of this wave's 32-row band)
        #pragma unroll
        for (int r = 0; r < 16; ++r) {
            float mx = fmaxf(fmaxf(acc[0][r], acc[1][r]), fmaxf(acc[2][r], acc[3][r]));
            mx = dpp16_max(mx);
            mx = fmaxf(mx, __shfl_xor(mx, 16, 64));   // combine rows-of-16 within half
            float s2 = __builtin_amdgcn_exp2f(acc[0][r] - mx)
                     + __builtin_amdgcn_exp2f(acc[1][r] - mx)
                     + __builtin_amdgcn_exp2f(acc[2][r] - mx)
                     + __builtin_amdgcn_exp2f(acc[3][r] - mx);
            s2 = dpp16_sum(s2);
            s2 += __shfl_xor(s2, 16, 64);
            if (l31 == 0) {
                const int row = rowbase + (r & 3) + 8 * (r >> 2) + 4 * hw;
                smP[row] = make_float2(mx, s2);
            }
        }
    }
    __syncthreads();

    // ---- coalesced store pass: smP -> partials ----
    #pragma unroll
    for (int it = 0; it < 2; ++it) {
        const int row = it * 512 + tid;
        const float2 v = smP[row];
        floatx2 w2; w2.x = v.x; w2.y = v.y;
        __builtin_nontemporal_store(w2, (floatx2*)(partials + (size_t)nb * NROWS + row));
    }
}

// ---- combine partials per row + positive logit (computed inline) + atomic mean ----
// Grid: 64 blocks x 256 threads. Block owns 16 rows; 16 part-groups of 32 parts.
__global__ __launch_bounds__(256)
void finalize_rows(const float2* __restrict__ partials,   // [NPART][1024]
                   const float* __restrict__ online,
                   const float* __restrict__ mom,
                   const float* __restrict__ temp,
                   float* __restrict__ out)
{
    const int t = threadIdx.x;
    __shared__ float2 sm[16][17];
    __shared__ float sm_pos[16];

    // phase 1: positive-pair logit, 16 threads per row (rows r2 = t>>4)
    {
        const float s = 1.0f / (temp[0] * LN2_F);
        const int r2 = t >> 4, c2 = t & 15;
        const float* po = online + (size_t)(blockIdx.x * 16 + r2) * DDIM + c2 * 16;
        const float* pm = mom    + (size_t)(blockIdx.x * 16 + r2) * DDIM + c2 * 16;
        float d = 0.f;
        #pragma unroll
        for (int w = 0; w < 4; ++w) {
            const floatx4 a = *(const floatx4*)(po + w * 4);
            const floatx4 b = *(const floatx4*)(pm + w * 4);
            d += a.x * b.x + a.y * b.y + a.z * b.z + a.w * b.w;
        }
        d = dpp16_sum(d);
        if (c2 == 0) sm_pos[r2] = d * s;    // base-2-domain positive logit
    }

    // phase 2: combine negative partials; rl = row-in-block, grp = part group
    const int rl  = t & 15;
    const int grp = t >> 4;
    const int row = blockIdx.x * 16 + rl;

    float M = -3.0e38f, S = 0.f;
    #pragma unroll 1
    for (int pb = 0; pb < 32; pb += 8) {
        float2 v[8];
        #pragma unroll
        for (int j = 0; j < 8; ++j)
            v[j] = partials[(size_t)(grp * 32 + pb + j) * NROWS + row];
        #pragma unroll
        for (int j = 0; j < 8; ++j) {
            const float M2 = fmaxf(M, v[j].x);
            S = S * __builtin_amdgcn_exp2f(M - M2) + v[j].y * __builtin_amdgcn_exp2f(v[j].x - M2);
            M = M2;
        }
    }
    sm[grp][rl] = make_float2(M, S);
    __syncthreads();

    if (t < 64) {
        float val = 0.f;
        if (t < 16) {
            float Mm = -3.0e38f, Ss = 0.f;
            #pragma unroll
            for (int g2 = 0; g2 < 16; ++g2) {
                const float2 v = sm[g2][t];
                const float M2 = fmaxf(Mm, v.x);
                Ss = Ss * __builtin_amdgcn_exp2f(Mm - M2) + v.y * __builtin_amdgcn_exp2f(v.x - M2);
                Mm = M2;
            }
            const float p  = sm_pos[t];
            const float M2 = fmaxf(Mm, p);
            const float L  = Ss * __builtin_amdgcn_exp2f(Mm - M2) + __builtin_amdgcn_exp2f(p - M2);
            val = (M2 + __builtin_amdgcn_logf(L) - p) * LN2_F;   // back to natural log
        }
        val += __shfl_xor(val, 1, 64);
        val += __shfl_xor(val, 2, 64);
        val += __shfl_xor(val, 4, 64);
        val += __shfl_xor(val, 8, 64);
        val += __shfl_xor(val, 16, 64);
        val += __shfl_xor(val, 32, 64);
        if (t == 0) atomicAdd(out, val * (1.0f / (float)NROWS));
    }
}

extern "C" void kernel_launch(void* const* d_in, const int* in_sizes, int n_in,
                              void* d_out, int out_size, void* d_ws, size_t ws_size,
                              hipStream_t stream)
{
    const float* online = (const float*)d_in[0];   // [1024][256]
    const float* mom    = (const float*)d_in[1];   // [1024][256]
    const float* queue  = (const float*)d_in[2];   // [256][65536]
    const float* temp   = (const float*)d_in[3];   // [1]
    float* out = (float*)d_out;

    // ws: Ab bf16 [1024][256] (512 KB) | partials float2 [512][1024] (4 MB)
    char* ws = (char*)d_ws;
    unsigned short* Ab = (unsigned short*)ws;
    float2* partials   = (float2*)(ws + 524288);

    conv_a<<<256, 256, 0, stream>>>(online, temp, Ab, out);
    gemm_softmax<<<KQ / BN, 512, 0, stream>>>(Ab, queue, partials);
    finalize_rows<<<64, 256, 0, stream>>>(partials, online, mom, temp, out);
}

// Round 8
// 146.571 us; speedup vs baseline: 1.0714x; 1.0714x over previous
//
#include <hip/hip_runtime.h>
#include <hip/hip_bf16.h>

// loss = mean_n( logsumexp([pos_n, (online@queue)_n]/t) - pos_n/t )   (fwd: alpha mix = identity)
// v15 = v11 VERBATIM (best: 512 thr, wave=32x128, acc[2][8], 16x16x32, 4 waves/SIMD,
//   single barrier) + s_setprio(1) around each step's 16-MFMA cluster (T5).
//   K-loop is barrier-free -> 16 waves/CU are phase-diverse -> priority arbitration
//   has something to arbitrate (m191 regime, not m190's lockstep null).
//   v12/v13/v14 post-mortems: M=64 tiles, A-ping-pong, 32x32 MFMA all regress ->
//   v11 shape is a sharp local optimum; residual gap is scheduling, attack with
//   scheduling primitives only.
//   (Round 7: resubmission — prior round was an infra failure, no bench data.)

#define NROWS 1024
#define DDIM  256
#define KQ    65536
#define BN    128
#define NPART 512
#define LN2_F 0.69314718055994531f

typedef short  short8  __attribute__((ext_vector_type(8)));
typedef float  floatx4 __attribute__((ext_vector_type(4)));

__device__ __forceinline__ unsigned short f2bf(float f) {
    unsigned int u = __float_as_uint(f);
    u += 0x7FFFu + ((u >> 16) & 1u);   // RNE
    return (unsigned short)(u >> 16);
}

// DPP lane-permute (row-of-16 scope). quad_perm xor1=0xB1, xor2=0x4E,
// row_half_mirror=0x141 (pairs quads), row_mirror=0x140 (pairs octets).
#define DPPMOV(x, ctrl) \
    __uint_as_float(__builtin_amdgcn_mov_dpp(__float_as_uint(x), (ctrl), 0xF, 0xF, true))

__device__ __forceinline__ float dpp16_max(float x) {
    x = fmaxf(x, DPPMOV(x, 0xB1));
    x = fmaxf(x, DPPMOV(x, 0x4E));
    x = fmaxf(x, DPPMOV(x, 0x141));
    x = fmaxf(x, DPPMOV(x, 0x140));
    return x;   // all 16 lanes of the row-of-16 hold the max
}
__device__ __forceinline__ float dpp16_sum(float x) {
    x += DPPMOV(x, 0xB1);
    x += DPPMOV(x, 0x4E);
    x += DPPMOV(x, 0x141);
    x += DPPMOV(x, 0x140);
    return x;
}

// ---- A conversion: bf16(A/(t*ln2)); also zeroes the output accumulator ----
__global__ __launch_bounds__(256)
void conv_a(const float* __restrict__ A, const float* __restrict__ temp,
            unsigned short* __restrict__ Ab, float* __restrict__ out)
{
    if (blockIdx.x == 0 && threadIdx.x == 0) out[0] = 0.0f;
    const float s = 1.0f / (temp[0] * LN2_F);
    const int i = blockIdx.x * 256 + threadIdx.x;       // 65536 threads, one float4 each
    const floatx4 v = ((const floatx4*)A)[i];
    ushort4 w;
    w.x = f2bf(v.x * s); w.y = f2bf(v.y * s);
    w.z = f2bf(v.z * s); w.w = f2bf(v.w * s);
    ((ushort4*)Ab)[i] = w;
}

// ---- fused GEMM + online-softmax partials. 512 blocks x 512 thr; block = one 128-col stripe ----
__global__ __launch_bounds__(512, 4)
void gemm_softmax(const unsigned short* __restrict__ Ab,   // [1024][256] bf16, pre-scaled
                  const float* __restrict__ Q,             // [256][65536] fp32
                  float2* __restrict__ partials)           // [NPART][1024]  (part-major)
{
    __shared__ __align__(16) unsigned short Bl[BN * DDIM];   // [n][k] bf16, 64 KB, swizzled

    const int tid  = threadIdx.x;
    const int lane = tid & 63;
    const int wave = tid >> 6;          // 0..7 (32-row bands within a group-pass)
    const int l15  = lane & 15;
    const int quad = lane >> 4;
    const int nb   = blockIdx.x;        // 0..511
    const int nbase = nb * BN;

    // ---- stage B once: Q[k][nbase..+127] fp32 -> Bl[n][k] bf16 (register transpose) ----
    // 1024 tasks (ko-octet x ny-quad), 2 per thread, one at a time (32 VGPR peak).
    #pragma unroll 1
    for (int iter = 0; iter < 2; ++iter) {
        const int t2 = iter * 512 + tid;
        const int ny = t2 & 31;             // n-quad (4 cols)
        const int ko = t2 >> 5;             // k-octet (8 rows), 0..31
        floatx4 v[8];
        #pragma unroll
        for (int j = 0; j < 8; ++j)
            v[j] = __builtin_nontemporal_load(
                       (const floatx4*)(Q + (size_t)(ko * 8 + j) * KQ + nbase + ny * 4));
        #pragma unroll
        for (int i2 = 0; i2 < 4; ++i2) {
            const int n = ny * 4 + i2;
            const int phys = ko ^ (n & 15);      // 16B-chunk XOR swizzle
            short8 w;
            #pragma unroll
            for (int j = 0; j < 8; ++j)
                w[j] = (short)f2bf(v[j][i2]);
            *(short8*)&Bl[n * DDIM + phys * 8] = w;
        }
    }
    __syncthreads();   // the ONLY barrier

    #pragma unroll 1
    for (int g = 0; g < 4; ++g) {
        const int rowbase = g * 256 + wave * 32;
        const unsigned short* apb = Ab + (size_t)(rowbase + l15) * DDIM + quad * 8;

        floatx4 acc[2][8] = {};
        short8 af[2], bf[8];

        #pragma unroll 1
        for (int s = 0; s < 8; ++s) {
            #pragma unroll
            for (int i = 0; i < 2; ++i)
                af[i] = *(const short8*)(apb + i * 16 * DDIM + s * 32);
            {
                const int vb = l15 * 512 + (((4 * s + quad) ^ l15) * 16);
                #pragma unroll
                for (int j = 0; j < 8; ++j)
                    bf[j] = *(const short8*)((const char*)Bl + vb + j * 8192);
            }
            __builtin_amdgcn_s_setprio(1);      // favor this wave while its MFMA cluster drains
            #pragma unroll
            for (int i = 0; i < 2; ++i)
                #pragma unroll
                for (int j = 0; j < 8; ++j)
                    acc[i][j] = __builtin_amdgcn_mfma_f32_16x16x32_bf16(af[i], bf[j], acc[i][j], 0, 0, 0);
            __builtin_amdgcn_s_setprio(0);
        }

        // epilogue: base-2 logits. C layout: col(n)=lane&15, row(m)=quad*4+reg (verified).
        #pragma unroll
        for (int i = 0; i < 2; ++i) {
            float2 tmp[4];
            #pragma unroll
            for (int r = 0; r < 4; ++r) {
                float mx = acc[i][0][r];
                #pragma unroll
                for (int j = 1; j < 8; ++j) mx = fmaxf(mx, acc[i][j][r]);
                mx = dpp16_max(mx);
                float s2 = 0.f;
                #pragma unroll
                for (int j = 0; j < 8; ++j)
                    s2 += __builtin_amdgcn_exp2f(acc[i][j][r] - mx);
                s2 = dpp16_sum(s2);
                tmp[r] = make_float2(mx, s2);
            }
            if (l15 == 0) {
                // 4 quad-leader lanes cover 128 contiguous bytes
                const int row = rowbase + i * 16 + quad * 4;
                floatx4* dst = (floatx4*)(partials + (size_t)nb * NROWS + row);
                floatx4 w0 = {tmp[0].x, tmp[0].y, tmp[1].x, tmp[1].y};
                floatx4 w1 = {tmp[2].x, tmp[2].y, tmp[3].x, tmp[3].y};
                __builtin_nontemporal_store(w0, dst);
                __builtin_nontemporal_store(w1, dst + 1);
            }
        }
    }
}

// ---- combine partials per row + positive logit (computed inline) + atomic mean ----
// Grid: 64 blocks x 256 threads. Block owns 16 rows; 16 part-groups of 32 parts.
__global__ __launch_bounds__(256)
void finalize_rows(const float2* __restrict__ partials,   // [NPART][1024]
                   const float* __restrict__ online,
                   const float* __restrict__ mom,
                   const float* __restrict__ temp,
                   float* __restrict__ out)
{
    const int t = threadIdx.x;
    __shared__ float2 sm[16][17];
    __shared__ float sm_pos[16];

    // phase 1: positive-pair logit, 16 threads per row (rows r2 = t>>4)
    {
        const float s = 1.0f / (temp[0] * LN2_F);
        const int r2 = t >> 4, c2 = t & 15;
        const float* po = online + (size_t)(blockIdx.x * 16 + r2) * DDIM + c2 * 16;
        const float* pm = mom    + (size_t)(blockIdx.x * 16 + r2) * DDIM + c2 * 16;
        float d = 0.f;
        #pragma unroll
        for (int w = 0; w < 4; ++w) {
            const floatx4 a = *(const floatx4*)(po + w * 4);
            const floatx4 b = *(const floatx4*)(pm + w * 4);
            d += a.x * b.x + a.y * b.y + a.z * b.z + a.w * b.w;
        }
        d = dpp16_sum(d);
        if (c2 == 0) sm_pos[r2] = d * s;    // base-2-domain positive logit
    }

    // phase 2: combine negative partials; rl = row-in-block, grp = part group
    const int rl  = t & 15;
    const int grp = t >> 4;
    const int row = blockIdx.x * 16 + rl;

    float M = -3.0e38f, S = 0.f;
    #pragma unroll 1
    for (int pb = 0; pb < 32; pb += 8) {
        float2 v[8];
        #pragma unroll
        for (int j = 0; j < 8; ++j)
            v[j] = partials[(size_t)(grp * 32 + pb + j) * NROWS + row];
        #pragma unroll
        for (int j = 0; j < 8; ++j) {
            const float M2 = fmaxf(M, v[j].x);
            S = S * __builtin_amdgcn_exp2f(M - M2) + v[j].y * __builtin_amdgcn_exp2f(v[j].x - M2);
            M = M2;
        }
    }
    sm[grp][rl] = make_float2(M, S);
    __syncthreads();

    if (t < 64) {
        float val = 0.f;
        if (t < 16) {
            float Mm = -3.0e38f, Ss = 0.f;
            #pragma unroll
            for (int g2 = 0; g2 < 16; ++g2) {
                const float2 v = sm[g2][t];
                const float M2 = fmaxf(Mm, v.x);
                Ss = Ss * __builtin_amdgcn_exp2f(Mm - M2) + v.y * __builtin_amdgcn_exp2f(v.x - M2);
                Mm = M2;
            }
            const float p  = sm_pos[t];
            const float M2 = fmaxf(Mm, p);
            const float L  = Ss * __builtin_amdgcn_exp2f(Mm - M2) + __builtin_amdgcn_exp2f(p - M2);
            val = (M2 + __builtin_amdgcn_logf(L) - p) * LN2_F;   // back to natural log
        }
        val += __shfl_xor(val, 1, 64);
        val += __shfl_xor(val, 2, 64);
        val += __shfl_xor(val, 4, 64);
        val += __shfl_xor(val, 8, 64);
        val += __shfl_xor(val, 16, 64);
        val += __shfl_xor(val, 32, 64);
        if (t == 0) atomicAdd(out, val * (1.0f / (float)NROWS));
    }
}

extern "C" void kernel_launch(void* const* d_in, const int* in_sizes, int n_in,
                              void* d_out, int out_size, void* d_ws, size_t ws_size,
                              hipStream_t stream)
{
    const float* online = (const float*)d_in[0];   // [1024][256]
    const float* mom    = (const float*)d_in[1];   // [1024][256]
    const float* queue  = (const float*)d_in[2];   // [256][65536]
    const float* temp   = (const float*)d_in[3];   // [1]
    float* out = (float*)d_out;

    // ws: Ab bf16 [1024][256] (512 KB) | partials float2 [512][1024] (4 MB)
    char* ws = (char*)d_ws;
    unsigned short* Ab = (unsigned short*)ws;
    float2* partials   = (float2*)(ws + 524288);

    conv_a<<<256, 256, 0, stream>>>(online, temp, Ab, out);
    gemm_softmax<<<KQ / BN, 512, 0, stream>>>(Ab, queue, partials);
    finalize_rows<<<64, 256, 0, stream>>>(partials, online, mom, temp, out);
}